// Round 1
// 86.054 us; speedup vs baseline: 1.0480x; 1.0480x over previous
//
#include <hip/hip_runtime.h>
#include <math.h>

// Problem constants (fixed by setup_inputs): N src points, M targets, D=3.
constexpr int N_SRC = 16384;
constexpr int M_TAR = 16384;

// R6: same instruction-exact inner loop as R5 (4.5 VALU ops per pair:
// 3 v_fma_f32 + 1 v_and_or_b32 + 0.5 v_min3_f32), but the staging is
// restructured as a double-buffered pipeline (T14 async-STAGE split):
//   - LDS = 2 x 2048-point float4 tiles (same 64 KB -> still 2 blocks/CU,
//     8 waves/SIMD)
//   - next tile's 6 global dwords are ISSUED before the compute phase
//     (sched_barrier(0) pins them above), and CONSUMED into ds_write_b128
//     after compute -> L2 latency (~200-400 cyc) hides under the 288-VALU
//     compute phase instead of sitting on the critical path
//   - ONE barrier per tile instead of two (write goes to the opposite
//     buffer; the end-of-tile barrier both publishes the writes and
//     retires the reads)
// Tile loop fully unrolled: all ds_read offsets become immediates across
// both buffers (max 61440 < 64K), row constants become SGPR immediates.
constexpr int BLOCKS = M_TAR / 32;     // 512
constexpr int TPB = 1024;              // 16 waves
constexpr int CHUNKS = 256;            // tid>>2
constexpr int TILE = 2048;             // sources per LDS tile (32 KB float4)
constexpr int TILES = N_SRC / TILE;    // 8
constexpr int ROWS_PT = TILE / CHUNKS; // 8 rows per tile
constexpr int IPT = ROWS_PT / 2;       // 4 source-pairs per tile per thread

__global__ void zero_out(float* __restrict__ out) {
    if (threadIdx.x == 0) out[0] = 0.0f;  // d_out poisoned 0xAA each launch
}

// (t & mask_v) | row_s  — mask forced to VGPR, uniform row rides the SGPR slot
__device__ __forceinline__ float embed_ao(float t, unsigned mask_v, unsigned row_s) {
    float r;
    asm("v_and_or_b32 %0, %1, %2, %3"
        : "=v"(r) : "v"(t), "v"(mask_v), "s"(row_s));
    return r;
}
// best = min(best, e0, e1) in one instruction (inputs never NaN here);
// "+v" ties dst to src0 so no v_mov is needed around it.
__device__ __forceinline__ void min3(float& b, float e0, float e1) {
    asm("v_min3_f32 %0, %0, %1, %2"
        : "+v"(b) : "v"(e0), "v"(e1));
}

__global__ __launch_bounds__(TPB, 8) void nn7(const float* __restrict__ src,
                                              const float* __restrict__ tar,
                                              float* __restrict__ out) {
    __shared__ float4 tile[2 * TILE];  // 64 KB double buffer; reused in tail

    const int tid   = threadIdx.x;
    const int g     = tid & 3;
    const int chunk = tid >> 2;    // 0..255
    const int tbase = blockIdx.x * 32;

    // 8 targets/thread, premultiplied by -2 so ||s||^2 folds into the fma chain
    float txm2[8], tym2[8], tzm2[8], best[8];
#pragma unroll
    for (int k = 0; k < 8; ++k) {
        int T = tbase + g + 4 * k;
        txm2[k] = -2.0f * tar[3 * T + 0];
        tym2[k] = -2.0f * tar[3 * T + 1];
        tzm2[k] = -2.0f * tar[3 * T + 2];
        best[k] = INFINITY;
    }

    // ---- prolog: stage tile 0 (points tid and tid+1024; contiguous b128 writes)
    {
        const float* q0 = src + 3 * tid;
        const float* q1 = src + 3 * (tid + TPB);
        float x0 = q0[0], y0 = q0[1], z0 = q0[2];
        float x1 = q1[0], y1 = q1[1], z1 = q1[2];
        tile[tid]       = make_float4(x0, y0, z0, fmaf(x0, x0, fmaf(y0, y0, z0 * z0)));
        tile[tid + TPB] = make_float4(x1, y1, z1, fmaf(x1, x1, fmaf(y1, y1, z1 * z1)));
    }
    __syncthreads();

    unsigned mask_v = 0xFFFFFFC0u;  // lives in a VGPR for v_and_or_b32

#pragma unroll
    for (int tl = 0; tl < TILES; ++tl) {
        // ---- issue prefetch for tile tl+1 (consumed after compute)
        float x0, y0, z0, x1, y1, z1;
        if (tl + 1 < TILES) {
            const float* q0 = src + 3 * ((tl + 1) * TILE + tid);
            const float* q1 = q0 + 3 * TPB;
            x0 = q0[0]; y0 = q0[1]; z0 = q0[2];
            x1 = q1[0]; y1 = q1[1]; z1 = q1[2];
            __builtin_amdgcn_sched_barrier(0);  // keep the issues above compute
        }

        // ---- scan current buffer: v(j) = ||s||^2 - 2 t.s ; imm ds offsets
        const int cb = (tl & 1) * TILE;
#pragma unroll
        for (int i = 0; i < IPT; ++i) {
            float4 s0 = tile[cb + (2 * i + 0) * CHUNKS + chunk];
            float4 s1 = tile[cb + (2 * i + 1) * CHUNKS + chunk];
            unsigned row0 = (unsigned)(tl * ROWS_PT + 2 * i + 0);  // uniform
            unsigned row1 = row0 + 1;                              // uniform
#pragma unroll
            for (int k = 0; k < 8; ++k) {
                float t0 = fmaf(s0.z, tzm2[k], s0.w);
                t0 = fmaf(s0.y, tym2[k], t0);
                t0 = fmaf(s0.x, txm2[k], t0);
                float t1 = fmaf(s1.z, tzm2[k], s1.w);
                t1 = fmaf(s1.y, tym2[k], t1);
                t1 = fmaf(s1.x, txm2[k], t1);
                float e0 = embed_ao(t0, mask_v, row0);
                float e1 = embed_ao(t1, mask_v, row1);
                min3(best[k], e0, e1);
            }
        }

        // ---- consume prefetch into the opposite buffer (vmcnt waited here,
        //      long after issue). Safe: everyone finished reading this buffer
        //      before the barrier that ended tile tl-1.
        if (tl + 1 < TILES) {
            const int wb = ((tl + 1) & 1) * TILE;
            tile[wb + tid]       = make_float4(x0, y0, z0, fmaf(x0, x0, fmaf(y0, y0, z0 * z0)));
            tile[wb + tid + TPB] = make_float4(x1, y1, z1, fmaf(x1, x1, fmaf(y1, y1, z1 * z1)));
        }
        __syncthreads();  // publishes writes for tl+1; retires reads of buffer tl
    }

    // ---- tail: resolve indices, merge 256 chunks per target, loss, atomic
    float* fv = (float*)tile;            // [32][256] values  (32 KB)
    int*   fj = (int*)tile + 32 * 256;   // [32][256] indices (32 KB)
#pragma unroll
    for (int k = 0; k < 8; ++k) {
        unsigned b = __float_as_uint(best[k]);
        int j  = (int)((b & 63u) * CHUNKS + chunk);  // j = row*256 + chunk
        int lt = g + 4 * k;
        fv[lt * CHUNKS + chunk] = __uint_as_float(b & 0xFFFFFFC0u);
        fj[lt * CHUNKS + chunk] = j;
    }
    __syncthreads();

    const int tprime = tid >> 5;   // 0..31: target this half-wave reduces
    const int sub    = tid & 31;
    float bv = fv[tprime * CHUNKS + sub];
    int   bj = fj[tprime * CHUNKS + sub];
#pragma unroll
    for (int m = 1; m < 8; ++m) {
        float v = fv[tprime * CHUNKS + sub + 32 * m];
        int   j = fj[tprime * CHUNKS + sub + 32 * m];
        if (v < bv) { bv = v; bj = j; }
    }
#pragma unroll
    for (int s = 16; s >= 1; s >>= 1) {   // xor<32 stays in the half-wave
        float vv = __shfl_xor(bv, s, 64);
        int   jj = __shfl_xor(bj, s, 64);
        if (vv < bv) { bv = vv; bj = jj; }
    }
    __syncthreads();  // done reading fv/fj; safe to reuse

    if (sub == 0) {
        int tt = tbase + tprime;
        // exact loss term from the winning index (reference formula)
        float dx = src[3 * bj + 0] - tar[3 * tt + 0];
        float dy = src[3 * bj + 1] - tar[3 * tt + 1];
        float dz = src[3 * bj + 2] - tar[3 * tt + 2];
        fv[tprime] = 0.5f * fmaf(dx, dx, fmaf(dy, dy, dz * dz));
    }
    __syncthreads();
    if (tid == 0) {
        float ssum = 0.0f;
#pragma unroll
        for (int i = 0; i < 32; ++i) ssum += fv[i];
        atomicAdd(out, ssum);  // device-scope, cross-XCD safe
    }
}

extern "C" void kernel_launch(void* const* d_in, const int* in_sizes, int n_in,
                              void* d_out, int out_size, void* d_ws, size_t ws_size,
                              hipStream_t stream) {
    const float* src = (const float*)d_in[0];  // src_V [N,3] fp32
    const float* tar = (const float*)d_in[1];  // tar_V [M,3] fp32
    float* out = (float*)d_out;                // scalar loss fp32
    (void)d_ws; (void)ws_size;

    zero_out<<<1, 64, 0, stream>>>(out);
    nn7<<<BLOCKS, TPB, 0, stream>>>(src, tar, out);
}